// Round 15
// baseline (416.918 us; speedup 1.0000x reference)
//
#include <hip/hip_runtime.h>
#include <hip/hip_bf16.h>

#define DEV __device__ __forceinline__

typedef __attribute__((ext_vector_type(8))) short bf16x8;
typedef __attribute__((ext_vector_type(4))) float f32x4;

constexpr int B = 4, S = 2048, D = 1024, H = 16, DK = 64, DFF = 4096;
constexpr int NT = B * S;  // 8192 tokens
constexpr float QSCALE = 0.125f * 1.44269504088896f;  // 1/sqrt(dk) * log2(e)

#if __has_builtin(__builtin_amdgcn_exp2f)
#define EXP2(x) __builtin_amdgcn_exp2f(x)
#else
#define EXP2(x) exp2f(x)
#endif

#define BARRIER()                         \
  asm volatile("" ::: "memory");          \
  __builtin_amdgcn_s_barrier();           \
  asm volatile("" ::: "memory")

DEV unsigned short f2bf(float f) {
  return __builtin_bit_cast(unsigned short, __float2bfloat16(f));
}
DEV float bf2f(unsigned short u) { return __uint_as_float((unsigned)u << 16); }

// async global->LDS 16B: lds base must be wave-uniform; each lane deposits at base+lane*16
DEV void gld16(unsigned short* ldsbase, const unsigned short* g, int lane) {
#if __has_builtin(__builtin_amdgcn_global_load_lds)
  __builtin_amdgcn_global_load_lds((const __attribute__((address_space(1))) unsigned int*)g,
                                   (__attribute__((address_space(3))) unsigned int*)ldsbase,
                                   16, 0, 0);
#else
  *(uint4*)(ldsbase + lane * 8) = *(const uint4*)g;
#endif
}

// ---------------- fp32 -> bf16 elementwise ----------------
__global__ __launch_bounds__(256) void cvt_bf16_kernel(const float* __restrict__ in,
                                                       unsigned short* __restrict__ out, int n) {
  int i = (blockIdx.x * 256 + threadIdx.x) * 8;
  if (i >= n) return;
  float4 a = *(const float4*)(in + i);
  float4 b = *(const float4*)(in + i + 4);
  uint4 o;
  o.x = f2bf(a.x) | ((unsigned)f2bf(a.y) << 16);
  o.y = f2bf(a.z) | ((unsigned)f2bf(a.w) << 16);
  o.z = f2bf(b.x) | ((unsigned)f2bf(b.y) << 16);
  o.w = f2bf(b.z) | ((unsigned)f2bf(b.w) << 16);
  *(uint4*)(out + i) = o;
}

// ---------------- all 6 weights: fp32 (R x C) -> bf16 transposed (C x R), one launch ------
__global__ __launch_bounds__(256) void transpose_cvt_all_kernel(
    const float* __restrict__ wq, const float* __restrict__ wk, const float* __restrict__ wv,
    const float* __restrict__ wo, const float* __restrict__ w1, const float* __restrict__ w2,
    unsigned short* __restrict__ wqkvT, unsigned short* __restrict__ woT,
    unsigned short* __restrict__ w1T, unsigned short* __restrict__ w2T) {
  __shared__ unsigned short tile[64][72];
  int bid = blockIdx.x;
  const float* in;
  unsigned short* out;
  int R, C, tb;
  if (bid < 1024) {  // wq|wk|wv|wo: 1024x1024, 256 tiles each
    int wsel = bid >> 8;
    tb = bid & 255;
    R = 1024; C = 1024;
    in = wsel == 0 ? wq : wsel == 1 ? wk : wsel == 2 ? wv : wo;
    out = wsel < 3 ? wqkvT + (size_t)wsel * D * D : woT;
  } else if (bid < 2048) {  // w1: 1024x4096
    tb = bid - 1024; R = 1024; C = 4096; in = w1; out = w1T;
  } else {                  // w2: 4096x1024
    tb = bid - 2048; R = 4096; C = 1024; in = w2; out = w2T;
  }
  int gx = C >> 6;
  int rb = (tb / gx) * 64, cb = (tb % gx) * 64;
  int t = threadIdx.x;
#pragma unroll
  for (int i = 0; i < 16; ++i) {
    int c = t + i * 256;
    int r = c >> 6, cc = c & 63;
    tile[cc][r] = f2bf(in[(size_t)(rb + r) * C + cb + cc]);
  }
  __syncthreads();
#pragma unroll
  for (int i = 0; i < 16; ++i) {
    int c = t + i * 256;
    int rr = c >> 6, cc = c & 63;
    out[(size_t)(cb + rr) * R + rb + cc] = tile[rr][cc];
  }
}

// ---------------- 256-tile GEMM, 8-phase K-half-plane schedule (R13, 419us) ----------------
// OMODE: 0 = fp32 out0, 1 = bf16 out0 (RELU opt), 3 = QKV routing, 4 = bf16 acc+bias+res
template <int BNW, int OMODE, bool RELU>
__global__ __launch_bounds__(512) void gemm256_kernel(const unsigned short* __restrict__ A,
                                                      const unsigned short* __restrict__ WT,
                                                      const float* __restrict__ bias0,
                                                      const float* __restrict__ bias1,
                                                      const float* __restrict__ bias2,
                                                      const unsigned short* __restrict__ res,
                                                      void* __restrict__ out0,
                                                      void* __restrict__ out1,
                                                      void* __restrict__ out2,
                                                      int M, int N, int K) {
  constexpr int BN = BNW * 64;
  __shared__ __align__(16) unsigned short sA[2][2][256 * 32];
  __shared__ __align__(16) unsigned short sB[2][2][BN * 32];

  int t = threadIdx.x, w = t >> 6, l = t & 63;
  int ll = l & 15, lh = l >> 4;

  // T1: XCD-aware swizzle (all grids here are divisible by 8)
  int lin = blockIdx.x, nwg = gridDim.x;
  int wg = (nwg & 7) == 0 ? (lin & 7) * (nwg >> 3) + (lin >> 3) : lin;
  int gx = N / BN;
  int bn = wg % gx, bm = wg / gx;

  const int wm = (w >> 2) * 128, wn = (w & 3) * (BNW * 16);
  const int ua = (lh ^ ((ll >> 1) & 3)) * 8;  // ds_read unit offset (shorts), per-thread const

  f32x4 acc[8][BNW] = {};

  const int pr = t >> 2, up = t & 3;
  const int ulog = up ^ ((pr >> 1) & 3);
  const unsigned short* gA0 = A + ((size_t)bm * 256 + pr) * K + ulog * 8;
  const unsigned short* gB0 = WT + ((size_t)bn * BN + pr) * K + ulog * 8;

  auto stgA = [&](int buf, int kh, int tile) {
    const unsigned short* s = gA0 + (size_t)tile * 64 + kh * 32;
    gld16(&sA[buf][kh][w * 512], s, l);
    gld16(&sA[buf][kh][4096 + w * 512], s + (size_t)128 * K, l);
  };
  auto stgB = [&](int buf, int kh, int tile) {
    const unsigned short* s = gB0 + (size_t)tile * 64 + kh * 32;
    gld16(&sB[buf][kh][w * 512], s, l);
    if constexpr (BNW == 4) gld16(&sB[buf][kh][4096 + w * 512], s + (size_t)128 * K, l);
  };

  const int NK = K >> 6;
  stgA(0, 0, 0); stgB(0, 0, 0);
  stgA(0, 1, 0); stgB(0, 1, 0);
  stgA(1, 0, 1); stgB(1, 0, 1);
  if constexpr (BNW == 4) asm volatile("s_waitcnt vmcnt(4)" ::: "memory");
  else                    asm volatile("s_waitcnt vmcnt(3)" ::: "memory");
  BARRIER();

  bf16x8 bfr[BNW];
  for (int it = 0; it < NK; it += 2) {
    const bool more = it + 2 < NK;
#pragma unroll
    for (int ph = 0; ph < 8; ++ph) {
      const int tb = ph >> 2;
      const int kh = (ph >> 1) & 1;
      const int mq = ph & 1;
      bf16x8 af[4];
      if (mq == 0) {
#pragma unroll
        for (int nt = 0; nt < BNW; ++nt)
          bfr[nt] = *(const bf16x8*)(&sB[tb][kh][(wn + nt * 16 + ll) * 32 + ua]);
      }
#pragma unroll
      for (int i = 0; i < 4; ++i)
        af[i] = *(const bf16x8*)(&sA[tb][kh][(wm + (mq * 4 + i) * 16 + ll) * 32 + ua]);
      if (ph == 0) stgA(1, 1, it + 1);
      else if (ph == 1) stgB(1, 1, it + 1);
      else if (more) {
        if (ph == 2) stgA(0, 0, it + 2);
        else if (ph == 3) stgB(0, 0, it + 2);
        else if (ph == 4) stgA(0, 1, it + 2);
        else if (ph == 5) stgB(0, 1, it + 2);
        else if (ph == 6) stgA(1, 0, it + 3);
        else stgB(1, 0, it + 3);
      }
      BARRIER();
      __builtin_amdgcn_s_setprio(1);
#pragma unroll
      for (int i = 0; i < 4; ++i)
#pragma unroll
        for (int nt = 0; nt < BNW; ++nt)
          acc[mq * 4 + i][nt] =
              __builtin_amdgcn_mfma_f32_16x16x32_bf16(af[i], bfr[nt], acc[mq * 4 + i][nt], 0, 0, 0);
      __builtin_amdgcn_s_setprio(0);
      if (ph == 3 || ph == 7) {
        if (more) {
          if constexpr (BNW == 4) asm volatile("s_waitcnt vmcnt(4)" ::: "memory");
          else                    asm volatile("s_waitcnt vmcnt(3)" ::: "memory");
        } else {
          asm volatile("s_waitcnt vmcnt(0)" ::: "memory");
        }
      }
      BARRIER();
    }
  }

  // epilogue
#pragma unroll
  for (int mt = 0; mt < 8; ++mt) {
#pragma unroll
    for (int nt = 0; nt < BNW; ++nt) {
      int col = bn * BN + wn + nt * 16 + ll;
      int row0 = bm * 256 + wm + mt * 16 + lh * 4;
      if constexpr (OMODE == 3) {
        int sec = col >> 10, c = col & 1023;
        float bv = (sec == 0 ? bias0 : (sec == 1 ? bias1 : bias2))[c];
        if (sec == 2) {  // per-head transposed V
          int b_ = row0 >> 11, s_ = row0 & 2047;
          size_t vr = ((size_t)(b_ * H + (c >> 6)) * 64 + (c & 63)) * S + s_;
          uint2 pk;
          pk.x = (unsigned)f2bf(acc[mt][nt][0] + bv) | ((unsigned)f2bf(acc[mt][nt][1] + bv) << 16);
          pk.y = (unsigned)f2bf(acc[mt][nt][2] + bv) | ((unsigned)f2bf(acc[mt][nt][3] + bv) << 16);
          *(uint2*)((unsigned short*)out2 + vr) = pk;
        } else {
          unsigned short* o = sec == 0 ? (unsigned short*)out0 : (unsigned short*)out1;
          float sc_ = sec == 0 ? QSCALE : 1.f;
#pragma unroll
          for (int r = 0; r < 4; ++r)
            o[(size_t)(row0 + r) * 1024 + c] = f2bf((acc[mt][nt][r] + bv) * sc_);
        }
      } else {
        float bv = bias0[col];
#pragma unroll
        for (int r = 0; r < 4; ++r) {
          float v = acc[mt][nt][r] + bv;
          if (RELU) v = fmaxf(v, 0.f);
          if (OMODE == 4) {
            v += bf2f(res[(size_t)(row0 + r) * N + col]);
            ((unsigned short*)out0)[(size_t)(row0 + r) * N + col] = f2bf(v);
          } else if (OMODE == 1)
            ((unsigned short*)out0)[(size_t)(row0 + r) * N + col] = f2bf(v);
          else
            ((float*)out0)[(size_t)(row0 + r) * N + col] = v;
        }
      }
    }
  }
}

// ---------------- Flash attention, LDS-staged K/V, full key range ----------------
// R14 body with q-range split to 128 rows/block (8 waves x 16 q-rows): grid 1024 blocks.
// LDS 50KB < 53.3KB => 3 blocks/CU resident (vs R14's 2) -> 24 waves/CU to hide the
// per-step vmcnt(0)+barrier drain (R14 counters: VALU 53% + MFMA 25% + ~35% dual-idle).
// Cost: 2x K/V fetch (~278MB, HBM was at 17% - headroom) + 2x staging issue (trivial).
__global__ __launch_bounds__(512) void attn_kernel(const unsigned short* __restrict__ q,
                                                   const unsigned short* __restrict__ k,
                                                   const unsigned short* __restrict__ vt,
                                                   unsigned short* __restrict__ ctx) {
  __shared__ __align__(16) unsigned short sK[2][64 * 64];
  __shared__ __align__(16) unsigned short sV[2][64 * 64];
  __shared__ __align__(16) unsigned short sP[8][16 * 72];
  int t = threadIdx.x, w = t >> 6, l = t & 63;
  int ll = l & 15, lh = l >> 4;
  int bh = blockIdx.y;
  int q0 = blockIdx.x * 128 + w * 16;
  const size_t base = (size_t)(bh >> 4) * S * D + (size_t)(bh & 15) * DK;
  const size_t vtbase = (size_t)bh * 64 * S;
  unsigned short* sPw = sP[w];

  const int srow = t >> 3;
  const int scol = 8 * ((t & 7) ^ (srow & 7));
  const unsigned short* gk = k + base + (size_t)srow * D + scol;
  const unsigned short* gv = vt + vtbase + (size_t)srow * S + scol;

  bf16x8 qf[2];
#pragma unroll
  for (int kk = 0; kk < 2; ++kk)
    qf[kk] = *(const bf16x8*)(q + base + (size_t)(q0 + ll) * D + kk * 32 + lh * 8);

  f32x4 cacc[4] = {};
  float m = -1e30f, lsum = 0.f;

  const int swz = (ll & 7) << 3;

  gld16(&sK[0][w * 512], gk, l);
  gld16(&sV[0][w * 512], gv, l);
  asm volatile("s_waitcnt vmcnt(0)" ::: "memory");
  __syncthreads();

  int cur = 0;
  for (int step = 0; step < 32; ++step) {
    int kb = step * 64;
    if (step < 31) {
      gld16(&sK[cur ^ 1][w * 512], gk + (size_t)(kb + 64) * D, l);
      gld16(&sV[cur ^ 1][w * 512], gv + (kb + 64), l);
    }
    const unsigned short* sKc = sK[cur];
    const unsigned short* sVc = sV[cur];

    bf16x8 kf[4][2];
#pragma unroll
    for (int nt = 0; nt < 4; ++nt)
#pragma unroll
      for (int kk = 0; kk < 2; ++kk)
        kf[nt][kk] = *(const bf16x8*)(sKc + (nt * 16 + ll) * 64 + ((kk * 32 + lh * 8) ^ swz));

    f32x4 sc[4] = {};
    __builtin_amdgcn_s_setprio(1);
#pragma unroll
    for (int nt = 0; nt < 4; ++nt) {
      sc[nt] = __builtin_amdgcn_mfma_f32_16x16x32_bf16(kf[nt][0], qf[0], sc[nt], 0, 0, 0);
      sc[nt] = __builtin_amdgcn_mfma_f32_16x16x32_bf16(kf[nt][1], qf[1], sc[nt], 0, 0, 0);
    }
    __builtin_amdgcn_s_setprio(0);
    // lane holds S[key = nt*16+lh*4+r][query = ll] in log2 units; reduce over 64 keys
    float tm = -1e30f;
#pragma unroll
    for (int nt = 0; nt < 4; ++nt)
#pragma unroll
      for (int r = 0; r < 4; ++r) tm = fmaxf(tm, sc[nt][r]);
    tm = fmaxf(tm, __shfl_xor(tm, 16));
    tm = fmaxf(tm, __shfl_xor(tm, 32));
    if (!__all(tm <= m + 8.0f)) {  // defer-max
      float mn = fmaxf(m, tm);
      float rsc = EXP2(m - mn);
      lsum *= rsc;
#pragma unroll
      for (int dt = 0; dt < 4; ++dt)
#pragma unroll
        for (int r = 0; r < 4; ++r) cacc[dt][r] *= rsc;
      m = mn;
    }
    float p[4][4], ps = 0.f;
#pragma unroll
    for (int nt = 0; nt < 4; ++nt)
#pragma unroll
      for (int r = 0; r < 4; ++r) {
        p[nt][r] = EXP2(sc[nt][r] - m);
        ps += p[nt][r];
      }
    ps += __shfl_xor(ps, 16);
    ps += __shfl_xor(ps, 32);
    lsum += ps;
#pragma unroll
    for (int nt = 0; nt < 4; ++nt) {
      uint2 pk;
      pk.x = (unsigned)f2bf(p[nt][0]) | ((unsigned)f2bf(p[nt][1]) << 16);
      pk.y = (unsigned)f2bf(p[nt][2]) | ((unsigned)f2bf(p[nt][3]) << 16);
      *(uint2*)(&sPw[ll * 72 + nt * 16 + lh * 4]) = pk;
    }
    bf16x8 pf[2];
    pf[0] = *(const bf16x8*)(&sPw[ll * 72 + lh * 8]);
    pf[1] = *(const bf16x8*)(&sPw[ll * 72 + 32 + lh * 8]);

    bf16x8 vf[4][2];
#pragma unroll
    for (int dt = 0; dt < 4; ++dt)
#pragma unroll
      for (int kt = 0; kt < 2; ++kt)
        vf[dt][kt] = *(const bf16x8*)(sVc + (dt * 16 + ll) * 64 + ((kt * 32 + lh * 8) ^ swz));
    __builtin_amdgcn_s_setprio(1);
#pragma unroll
    for (int dt = 0; dt < 4; ++dt)
#pragma unroll
      for (int kt = 0; kt < 2; ++kt)
        cacc[dt] = __builtin_amdgcn_mfma_f32_16x16x32_bf16(pf[kt], vf[dt][kt], cacc[dt], 0, 0, 0);
    __builtin_amdgcn_s_setprio(0);

    asm volatile("s_waitcnt vmcnt(0)" ::: "memory");
    __syncthreads();
    cur ^= 1;
  }

  // epilogue: normalized bf16 ctx directly
  float inv[4];
#pragma unroll
  for (int r = 0; r < 4; ++r) inv[r] = 1.0f / __shfl(lsum, lh * 4 + r);
#pragma unroll
  for (int dt = 0; dt < 4; ++dt) {
#pragma unroll
    for (int r = 0; r < 4; ++r) {
      int row = q0 + lh * 4 + r;
      ctx[base + (size_t)row * D + dt * 16 + ll] = f2bf(cacc[dt][r] * inv[r]);
    }
  }
}

// ---------------- LayerNorm of a single bf16 buffer (residual pre-added) ----------------
template <bool OUT_F32>
__global__ __launch_bounds__(256) void ln_kernel(const unsigned short* __restrict__ a,
                                                 const float* __restrict__ gamma,
                                                 const float* __restrict__ beta,
                                                 float* __restrict__ outf,
                                                 unsigned short* __restrict__ outb) {
  __shared__ float sred[8];
  size_t row = blockIdx.x;
  int t = threadIdx.x;
  size_t bidx = row * D + t * 4;
  ushort4 u = *(const ushort4*)(a + bidx);
  float4 x;
  x.x = bf2f(u.x); x.y = bf2f(u.y); x.z = bf2f(u.z); x.w = bf2f(u.w);

  float s = x.x + x.y + x.z + x.w;
#pragma unroll
  for (int msk = 32; msk; msk >>= 1) s += __shfl_xor(s, msk);
  if ((t & 63) == 0) sred[t >> 6] = s;
  __syncthreads();
  float mu = (sred[0] + sred[1] + sred[2] + sred[3]) * (1.f / D);

  float dx = x.x - mu, dy = x.y - mu, dz = x.z - mu, dw = x.w - mu;
  float sq = dx * dx + dy * dy + dz * dz + dw * dw;
#pragma unroll
  for (int msk = 32; msk; msk >>= 1) sq += __shfl_xor(sq, msk);
  __syncthreads();
  if ((t & 63) == 0) sred[t >> 6] = sq;
  __syncthreads();
  float var = (sred[0] + sred[1] + sred[2] + sred[3]) * (1.f / D);
  float rs = rsqrtf(var + 1e-5f);

  float4 g = *(const float4*)(gamma + t * 4);
  float4 be = *(const float4*)(beta + t * 4);
  float4 y;
  y.x = dx * rs * g.x + be.x;
  y.y = dy * rs * g.y + be.y;
  y.z = dz * rs * g.z + be.z;
  y.w = dw * rs * g.w + be.w;
  if (OUT_F32) {
    *(float4*)(outf + bidx) = y;
  } else {
    uint2 o;
    o.x = (unsigned)f2bf(y.x) | ((unsigned)f2bf(y.y) << 16);
    o.y = (unsigned)f2bf(y.z) | ((unsigned)f2bf(y.w) << 16);
    *(uint2*)(outb + bidx) = o;
  }
}

extern "C" void kernel_launch(void* const* d_in, const int* in_sizes, int n_in,
                              void* d_out, int out_size, void* d_ws, size_t ws_size,
                              hipStream_t stream) {
  const float* x   = (const float*)d_in[0];
  const float* wq  = (const float*)d_in[1];
  const float* bq  = (const float*)d_in[2];
  const float* wk  = (const float*)d_in[3];
  const float* bk  = (const float*)d_in[4];
  const float* wv  = (const float*)d_in[5];
  const float* bv  = (const float*)d_in[6];
  const float* wo  = (const float*)d_in[7];
  const float* bo  = (const float*)d_in[8];
  const float* w1  = (const float*)d_in[9];
  const float* b1  = (const float*)d_in[10];
  const float* w2  = (const float*)d_in[11];
  const float* b2  = (const float*)d_in[12];
  const float* g1  = (const float*)d_in[13];
  const float* be1 = (const float*)d_in[14];
  const float* g2  = (const float*)d_in[15];
  const float* be2 = (const float*)d_in[16];

  char* ws = (char*)d_ws;
  size_t off = 0;
  auto alloc = [&](size_t bytes) {
    char* p = ws + off;
    off += (bytes + 255) & ~(size_t)255;
    return p;
  };

  unsigned short* wqkvT = (unsigned short*)alloc((size_t)3 * D * D * 2);  // [3072][1024]
  unsigned short* woT = (unsigned short*)alloc((size_t)D * D * 2);
  unsigned short* w1T = (unsigned short*)alloc((size_t)D * DFF * 2);
  unsigned short* w2T = (unsigned short*)alloc((size_t)DFF * D * 2);
  unsigned short* xb  = (unsigned short*)alloc((size_t)NT * D * 2);   // reused as x1b
  unsigned short* big = (unsigned short*)alloc((size_t)NT * DFF * 2); // q|k|ctx|vt, later ff
  unsigned short* qb  = big;
  unsigned short* kb_ = big + (size_t)NT * D;
  unsigned short* ctb = big + (size_t)2 * NT * D;
  unsigned short* vtb = big + (size_t)3 * NT * D;                     // per-head V^T (16 MiB)
  unsigned short* O1  = (unsigned short*)alloc((size_t)NT * D * 2);   // attn_out (WO out)
  unsigned short* O2  = (unsigned short*)alloc((size_t)NT * D * 2);   // ff2
  unsigned short* x1b = xb;
  unsigned short* ffb = big;
  unsigned short* attn_out = O1;  // WO output (bf16, residual fused)
  unsigned short* ff2 = O2;       // FF2 output (bf16, residual fused)
  (void)ws_size; (void)in_sizes; (void)n_in; (void)out_size;

  // 1. convert x + all weights (transposed) to bf16 in 2 launches
  cvt_bf16_kernel<<<NT * D / 2048, 256, 0, stream>>>(x, xb, NT * D);
  transpose_cvt_all_kernel<<<3072, 256, 0, stream>>>(wq, wk, wv, wo, w1, w2,
                                                     wqkvT, woT, w1T, w2T);

  // 2. fused QKV projection (Q pre-scaled into log2 domain; V written per-head transposed)
  gemm256_kernel<4, 3, false><<<(3 * D / 256) * (NT / 256), 512, 0, stream>>>(
      xb, wqkvT, bq, bk, bv, nullptr, qb, kb_, vtb, NT, 3 * D, D);

  // 3. attention (full key range, 128 q-rows/block for 3-blocks/CU residency)
  attn_kernel<<<dim3(S / 128, B * H), 512, 0, stream>>>(qb, kb_, vtb, ctb);

  // 4. output projection with fused residual: attn_out = ctx @ wo + bo + x  (bf16)
  gemm256_kernel<2, 4, false><<<(D / 128) * (NT / 256), 512, 0, stream>>>(
      ctb, woT, bo, nullptr, nullptr, xb, attn_out, nullptr, nullptr, NT, D, D);

  // 5. x1 = LN(attn_out) -> bf16
  ln_kernel<false><<<NT, 256, 0, stream>>>(attn_out, g1, be1, nullptr, x1b);

  // 6. FF (FF2 with fused bf16 residual: ff2 = relu(x1 @ w1 + b1) @ w2 + b2 + x1)
  gemm256_kernel<4, 1, true><<<(DFF / 256) * (NT / 256), 512, 0, stream>>>(
      x1b, w1T, b1, nullptr, nullptr, nullptr, ffb, nullptr, nullptr, NT, DFF, D);
  gemm256_kernel<2, 4, false><<<(D / 128) * (NT / 256), 512, 0, stream>>>(
      ffb, w2T, b2, nullptr, nullptr, x1b, ff2, nullptr, nullptr, NT, D, DFF);

  // 7. out = LN(ff2) -> fp32
  ln_kernel<true><<<NT, 256, 0, stream>>>(ff2, g2, be2, (float*)d_out, nullptr);
}

// Round 16
// 412.849 us; speedup vs baseline: 1.0099x; 1.0099x over previous
//
#include <hip/hip_runtime.h>
#include <hip/hip_bf16.h>

#define DEV __device__ __forceinline__

typedef __attribute__((ext_vector_type(8))) short bf16x8;
typedef __attribute__((ext_vector_type(4))) float f32x4;

constexpr int B = 4, S = 2048, D = 1024, H = 16, DK = 64, DFF = 4096;
constexpr int NT = B * S;  // 8192 tokens
constexpr float QSCALE = 0.125f * 1.44269504088896f;  // 1/sqrt(dk) * log2(e)

#if __has_builtin(__builtin_amdgcn_exp2f)
#define EXP2(x) __builtin_amdgcn_exp2f(x)
#else
#define EXP2(x) exp2f(x)
#endif

#define BARRIER()                         \
  asm volatile("" ::: "memory");          \
  __builtin_amdgcn_s_barrier();           \
  asm volatile("" ::: "memory")

DEV unsigned short f2bf(float f) {
  return __builtin_bit_cast(unsigned short, __float2bfloat16(f));
}
DEV float bf2f(unsigned short u) { return __uint_as_float((unsigned)u << 16); }

// async global->LDS 16B: lds base must be wave-uniform; each lane deposits at base+lane*16
DEV void gld16(unsigned short* ldsbase, const unsigned short* g, int lane) {
#if __has_builtin(__builtin_amdgcn_global_load_lds)
  __builtin_amdgcn_global_load_lds((const __attribute__((address_space(1))) unsigned int*)g,
                                   (__attribute__((address_space(3))) unsigned int*)ldsbase,
                                   16, 0, 0);
#else
  *(uint4*)(ldsbase + lane * 8) = *(const uint4*)g;
#endif
}

// ---------------- fp32 -> bf16 elementwise ----------------
__global__ __launch_bounds__(256) void cvt_bf16_kernel(const float* __restrict__ in,
                                                       unsigned short* __restrict__ out, int n) {
  int i = (blockIdx.x * 256 + threadIdx.x) * 8;
  if (i >= n) return;
  float4 a = *(const float4*)(in + i);
  float4 b = *(const float4*)(in + i + 4);
  uint4 o;
  o.x = f2bf(a.x) | ((unsigned)f2bf(a.y) << 16);
  o.y = f2bf(a.z) | ((unsigned)f2bf(a.w) << 16);
  o.z = f2bf(b.x) | ((unsigned)f2bf(b.y) << 16);
  o.w = f2bf(b.z) | ((unsigned)f2bf(b.w) << 16);
  *(uint4*)(out + i) = o;
}

// ---------------- all 6 weights: fp32 (R x C) -> bf16 transposed (C x R), one launch ------
__global__ __launch_bounds__(256) void transpose_cvt_all_kernel(
    const float* __restrict__ wq, const float* __restrict__ wk, const float* __restrict__ wv,
    const float* __restrict__ wo, const float* __restrict__ w1, const float* __restrict__ w2,
    unsigned short* __restrict__ wqkvT, unsigned short* __restrict__ woT,
    unsigned short* __restrict__ w1T, unsigned short* __restrict__ w2T) {
  __shared__ unsigned short tile[64][72];
  int bid = blockIdx.x;
  const float* in;
  unsigned short* out;
  int R, C, tb;
  if (bid < 1024) {  // wq|wk|wv|wo: 1024x1024, 256 tiles each
    int wsel = bid >> 8;
    tb = bid & 255;
    R = 1024; C = 1024;
    in = wsel == 0 ? wq : wsel == 1 ? wk : wsel == 2 ? wv : wo;
    out = wsel < 3 ? wqkvT + (size_t)wsel * D * D : woT;
  } else if (bid < 2048) {  // w1: 1024x4096
    tb = bid - 1024; R = 1024; C = 4096; in = w1; out = w1T;
  } else {                  // w2: 4096x1024
    tb = bid - 2048; R = 4096; C = 1024; in = w2; out = w2T;
  }
  int gx = C >> 6;
  int rb = (tb / gx) * 64, cb = (tb % gx) * 64;
  int t = threadIdx.x;
#pragma unroll
  for (int i = 0; i < 16; ++i) {
    int c = t + i * 256;
    int r = c >> 6, cc = c & 63;
    tile[cc][r] = f2bf(in[(size_t)(rb + r) * C + cb + cc]);
  }
  __syncthreads();
#pragma unroll
  for (int i = 0; i < 16; ++i) {
    int c = t + i * 256;
    int rr = c >> 6, cc = c & 63;
    out[(size_t)(cb + rr) * R + rb + cc] = tile[rr][cc];
  }
}

// ---------------- 256-tile GEMM, 8-phase K-half-plane schedule (R13, 419us) ----------------
// OMODE: 0 = fp32 out0, 1 = bf16 out0 (RELU opt), 3 = QKV routing, 4 = bf16 acc+bias+res
template <int BNW, int OMODE, bool RELU>
__global__ __launch_bounds__(512) void gemm256_kernel(const unsigned short* __restrict__ A,
                                                      const unsigned short* __restrict__ WT,
                                                      const float* __restrict__ bias0,
                                                      const float* __restrict__ bias1,
                                                      const float* __restrict__ bias2,
                                                      const unsigned short* __restrict__ res,
                                                      void* __restrict__ out0,
                                                      void* __restrict__ out1,
                                                      void* __restrict__ out2,
                                                      int M, int N, int K) {
  constexpr int BN = BNW * 64;
  __shared__ __align__(16) unsigned short sA[2][2][256 * 32];
  __shared__ __align__(16) unsigned short sB[2][2][BN * 32];

  int t = threadIdx.x, w = t >> 6, l = t & 63;
  int ll = l & 15, lh = l >> 4;

  // T1: XCD-aware swizzle (all grids here are divisible by 8)
  int lin = blockIdx.x, nwg = gridDim.x;
  int wg = (nwg & 7) == 0 ? (lin & 7) * (nwg >> 3) + (lin >> 3) : lin;
  int gx = N / BN;
  int bn = wg % gx, bm = wg / gx;

  const int wm = (w >> 2) * 128, wn = (w & 3) * (BNW * 16);
  const int ua = (lh ^ ((ll >> 1) & 3)) * 8;  // ds_read unit offset (shorts), per-thread const

  f32x4 acc[8][BNW] = {};

  const int pr = t >> 2, up = t & 3;
  const int ulog = up ^ ((pr >> 1) & 3);
  const unsigned short* gA0 = A + ((size_t)bm * 256 + pr) * K + ulog * 8;
  const unsigned short* gB0 = WT + ((size_t)bn * BN + pr) * K + ulog * 8;

  auto stgA = [&](int buf, int kh, int tile) {
    const unsigned short* s = gA0 + (size_t)tile * 64 + kh * 32;
    gld16(&sA[buf][kh][w * 512], s, l);
    gld16(&sA[buf][kh][4096 + w * 512], s + (size_t)128 * K, l);
  };
  auto stgB = [&](int buf, int kh, int tile) {
    const unsigned short* s = gB0 + (size_t)tile * 64 + kh * 32;
    gld16(&sB[buf][kh][w * 512], s, l);
    if constexpr (BNW == 4) gld16(&sB[buf][kh][4096 + w * 512], s + (size_t)128 * K, l);
  };

  const int NK = K >> 6;
  stgA(0, 0, 0); stgB(0, 0, 0);
  stgA(0, 1, 0); stgB(0, 1, 0);
  stgA(1, 0, 1); stgB(1, 0, 1);
  if constexpr (BNW == 4) asm volatile("s_waitcnt vmcnt(4)" ::: "memory");
  else                    asm volatile("s_waitcnt vmcnt(3)" ::: "memory");
  BARRIER();

  bf16x8 bfr[BNW];
  for (int it = 0; it < NK; it += 2) {
    const bool more = it + 2 < NK;
#pragma unroll
    for (int ph = 0; ph < 8; ++ph) {
      const int tb = ph >> 2;
      const int kh = (ph >> 1) & 1;
      const int mq = ph & 1;
      bf16x8 af[4];
      if (mq == 0) {
#pragma unroll
        for (int nt = 0; nt < BNW; ++nt)
          bfr[nt] = *(const bf16x8*)(&sB[tb][kh][(wn + nt * 16 + ll) * 32 + ua]);
      }
#pragma unroll
      for (int i = 0; i < 4; ++i)
        af[i] = *(const bf16x8*)(&sA[tb][kh][(wm + (mq * 4 + i) * 16 + ll) * 32 + ua]);
      if (ph == 0) stgA(1, 1, it + 1);
      else if (ph == 1) stgB(1, 1, it + 1);
      else if (more) {
        if (ph == 2) stgA(0, 0, it + 2);
        else if (ph == 3) stgB(0, 0, it + 2);
        else if (ph == 4) stgA(0, 1, it + 2);
        else if (ph == 5) stgB(0, 1, it + 2);
        else if (ph == 6) stgA(1, 0, it + 3);
        else stgB(1, 0, it + 3);
      }
      BARRIER();
      __builtin_amdgcn_s_setprio(1);
#pragma unroll
      for (int i = 0; i < 4; ++i)
#pragma unroll
        for (int nt = 0; nt < BNW; ++nt)
          acc[mq * 4 + i][nt] =
              __builtin_amdgcn_mfma_f32_16x16x32_bf16(af[i], bfr[nt], acc[mq * 4 + i][nt], 0, 0, 0);
      __builtin_amdgcn_s_setprio(0);
      if (ph == 3 || ph == 7) {
        if (more) {
          if constexpr (BNW == 4) asm volatile("s_waitcnt vmcnt(4)" ::: "memory");
          else                    asm volatile("s_waitcnt vmcnt(3)" ::: "memory");
        } else {
          asm volatile("s_waitcnt vmcnt(0)" ::: "memory");
        }
      }
      BARRIER();
    }
  }

  // epilogue
#pragma unroll
  for (int mt = 0; mt < 8; ++mt) {
#pragma unroll
    for (int nt = 0; nt < BNW; ++nt) {
      int col = bn * BN + wn + nt * 16 + ll;
      int row0 = bm * 256 + wm + mt * 16 + lh * 4;
      if constexpr (OMODE == 3) {
        int sec = col >> 10, c = col & 1023;
        float bv = (sec == 0 ? bias0 : (sec == 1 ? bias1 : bias2))[c];
        if (sec == 2) {  // per-head transposed V
          int b_ = row0 >> 11, s_ = row0 & 2047;
          size_t vr = ((size_t)(b_ * H + (c >> 6)) * 64 + (c & 63)) * S + s_;
          uint2 pk;
          pk.x = (unsigned)f2bf(acc[mt][nt][0] + bv) | ((unsigned)f2bf(acc[mt][nt][1] + bv) << 16);
          pk.y = (unsigned)f2bf(acc[mt][nt][2] + bv) | ((unsigned)f2bf(acc[mt][nt][3] + bv) << 16);
          *(uint2*)((unsigned short*)out2 + vr) = pk;
        } else {
          unsigned short* o = sec == 0 ? (unsigned short*)out0 : (unsigned short*)out1;
          float sc_ = sec == 0 ? QSCALE : 1.f;
#pragma unroll
          for (int r = 0; r < 4; ++r)
            o[(size_t)(row0 + r) * 1024 + c] = f2bf((acc[mt][nt][r] + bv) * sc_);
        }
      } else {
        float bv = bias0[col];
#pragma unroll
        for (int r = 0; r < 4; ++r) {
          float v = acc[mt][nt][r] + bv;
          if (RELU) v = fmaxf(v, 0.f);
          if (OMODE == 4) {
            v += bf2f(res[(size_t)(row0 + r) * N + col]);
            ((unsigned short*)out0)[(size_t)(row0 + r) * N + col] = f2bf(v);
          } else if (OMODE == 1)
            ((unsigned short*)out0)[(size_t)(row0 + r) * N + col] = f2bf(v);
          else
            ((float*)out0)[(size_t)(row0 + r) * N + col] = v;
        }
      }
    }
  }
}

// ---------------- Flash attention, LDS-staged K/V, full key range (R14, 114us) ----------------
// 8 waves x 32 q-rows = 256 q-rows/block (R15's 16-row split regressed: halves MFMA per
// barrier step at constant overhead). Defer-max softmax, 64-VGPR measured config.
__global__ __launch_bounds__(512) void attn_kernel(const unsigned short* __restrict__ q,
                                                   const unsigned short* __restrict__ k,
                                                   const unsigned short* __restrict__ vt,
                                                   unsigned short* __restrict__ ctx) {
  __shared__ __align__(16) unsigned short sK[2][64 * 64];
  __shared__ __align__(16) unsigned short sV[2][64 * 64];
  __shared__ __align__(16) unsigned short sP[8][16 * 72];
  int t = threadIdx.x, w = t >> 6, l = t & 63;
  int ll = l & 15, lh = l >> 4;
  int bh = blockIdx.y;
  int q0 = blockIdx.x * 256 + w * 32;
  const size_t base = (size_t)(bh >> 4) * S * D + (size_t)(bh & 15) * DK;
  const size_t vtbase = (size_t)bh * 64 * S;
  unsigned short* sPw = sP[w];

  const int srow = t >> 3;
  const int scol = 8 * ((t & 7) ^ (srow & 7));
  const unsigned short* gk = k + base + (size_t)srow * D + scol;
  const unsigned short* gv = vt + vtbase + (size_t)srow * S + scol;

  bf16x8 qf[2][2];
#pragma unroll
  for (int qs = 0; qs < 2; ++qs)
#pragma unroll
    for (int kk = 0; kk < 2; ++kk)
      qf[qs][kk] = *(const bf16x8*)(q + base + (size_t)(q0 + qs * 16 + ll) * D + kk * 32 + lh * 8);

  f32x4 cacc[2][4] = {};
  float m[2] = {-1e30f, -1e30f}, lsum[2] = {0.f, 0.f};

  const int swz = (ll & 7) << 3;

  gld16(&sK[0][w * 512], gk, l);
  gld16(&sV[0][w * 512], gv, l);
  asm volatile("s_waitcnt vmcnt(0)" ::: "memory");
  __syncthreads();

  int cur = 0;
  for (int step = 0; step < 32; ++step) {
    int kb = step * 64;
    if (step < 31) {
      gld16(&sK[cur ^ 1][w * 512], gk + (size_t)(kb + 64) * D, l);
      gld16(&sV[cur ^ 1][w * 512], gv + (kb + 64), l);
    }
    const unsigned short* sKc = sK[cur];
    const unsigned short* sVc = sV[cur];

    bf16x8 kf[4][2];
#pragma unroll
    for (int nt = 0; nt < 4; ++nt)
#pragma unroll
      for (int kk = 0; kk < 2; ++kk)
        kf[nt][kk] = *(const bf16x8*)(sKc + (nt * 16 + ll) * 64 + ((kk * 32 + lh * 8) ^ swz));

    bf16x8 pf[2][2];
#pragma unroll
    for (int qs = 0; qs < 2; ++qs) {
      f32x4 sc[4] = {};
      __builtin_amdgcn_s_setprio(1);
#pragma unroll
      for (int nt = 0; nt < 4; ++nt) {
        sc[nt] = __builtin_amdgcn_mfma_f32_16x16x32_bf16(kf[nt][0], qf[qs][0], sc[nt], 0, 0, 0);
        sc[nt] = __builtin_amdgcn_mfma_f32_16x16x32_bf16(kf[nt][1], qf[qs][1], sc[nt], 0, 0, 0);
      }
      __builtin_amdgcn_s_setprio(0);
      float tm = -1e30f;
#pragma unroll
      for (int nt = 0; nt < 4; ++nt)
#pragma unroll
        for (int r = 0; r < 4; ++r) tm = fmaxf(tm, sc[nt][r]);
      tm = fmaxf(tm, __shfl_xor(tm, 16));
      tm = fmaxf(tm, __shfl_xor(tm, 32));
      if (!__all(tm <= m[qs] + 8.0f)) {  // defer-max
        float mn = fmaxf(m[qs], tm);
        float rsc = EXP2(m[qs] - mn);
        lsum[qs] *= rsc;
#pragma unroll
        for (int dt = 0; dt < 4; ++dt)
#pragma unroll
          for (int r = 0; r < 4; ++r) cacc[qs][dt][r] *= rsc;
        m[qs] = mn;
      }
      float p[4][4], ps = 0.f;
#pragma unroll
      for (int nt = 0; nt < 4; ++nt)
#pragma unroll
        for (int r = 0; r < 4; ++r) {
          p[nt][r] = EXP2(sc[nt][r] - m[qs]);
          ps += p[nt][r];
        }
      ps += __shfl_xor(ps, 16);
      ps += __shfl_xor(ps, 32);
      lsum[qs] += ps;
#pragma unroll
      for (int nt = 0; nt < 4; ++nt) {
        uint2 pk;
        pk.x = (unsigned)f2bf(p[nt][0]) | ((unsigned)f2bf(p[nt][1]) << 16);
        pk.y = (unsigned)f2bf(p[nt][2]) | ((unsigned)f2bf(p[nt][3]) << 16);
        *(uint2*)(&sPw[ll * 72 + nt * 16 + lh * 4]) = pk;
      }
      pf[qs][0] = *(const bf16x8*)(&sPw[ll * 72 + lh * 8]);
      pf[qs][1] = *(const bf16x8*)(&sPw[ll * 72 + 32 + lh * 8]);
    }

    bf16x8 vf[4][2];
#pragma unroll
    for (int dt = 0; dt < 4; ++dt)
#pragma unroll
      for (int kt = 0; kt < 2; ++kt)
        vf[dt][kt] = *(const bf16x8*)(sVc + (dt * 16 + ll) * 64 + ((kt * 32 + lh * 8) ^ swz));
    __builtin_amdgcn_s_setprio(1);
#pragma unroll
    for (int qs = 0; qs < 2; ++qs)
#pragma unroll
      for (int dt = 0; dt < 4; ++dt)
#pragma unroll
        for (int kt = 0; kt < 2; ++kt)
          cacc[qs][dt] = __builtin_amdgcn_mfma_f32_16x16x32_bf16(pf[qs][kt], vf[dt][kt], cacc[qs][dt], 0, 0, 0);
    __builtin_amdgcn_s_setprio(0);

    asm volatile("s_waitcnt vmcnt(0)" ::: "memory");
    __syncthreads();
    cur ^= 1;
  }

  // epilogue: normalized bf16 ctx directly
#pragma unroll
  for (int qs = 0; qs < 2; ++qs) {
    float inv[4];
#pragma unroll
    for (int r = 0; r < 4; ++r) inv[r] = 1.0f / __shfl(lsum[qs], lh * 4 + r);
#pragma unroll
    for (int dt = 0; dt < 4; ++dt) {
#pragma unroll
      for (int r = 0; r < 4; ++r) {
        int row = q0 + qs * 16 + lh * 4 + r;
        ctx[base + (size_t)row * D + dt * 16 + ll] = f2bf(cacc[qs][dt][r] * inv[r]);
      }
    }
  }
}

// ---------------- LayerNorm of a single bf16 buffer (residual pre-added) ----------------
template <bool OUT_F32>
__global__ __launch_bounds__(256) void ln_kernel(const unsigned short* __restrict__ a,
                                                 const float* __restrict__ gamma,
                                                 const float* __restrict__ beta,
                                                 float* __restrict__ outf,
                                                 unsigned short* __restrict__ outb) {
  __shared__ float sred[8];
  size_t row = blockIdx.x;
  int t = threadIdx.x;
  size_t bidx = row * D + t * 4;
  ushort4 u = *(const ushort4*)(a + bidx);
  float4 x;
  x.x = bf2f(u.x); x.y = bf2f(u.y); x.z = bf2f(u.z); x.w = bf2f(u.w);

  float s = x.x + x.y + x.z + x.w;
#pragma unroll
  for (int msk = 32; msk; msk >>= 1) s += __shfl_xor(s, msk);
  if ((t & 63) == 0) sred[t >> 6] = s;
  __syncthreads();
  float mu = (sred[0] + sred[1] + sred[2] + sred[3]) * (1.f / D);

  float dx = x.x - mu, dy = x.y - mu, dz = x.z - mu, dw = x.w - mu;
  float sq = dx * dx + dy * dy + dz * dz + dw * dw;
#pragma unroll
  for (int msk = 32; msk; msk >>= 1) sq += __shfl_xor(sq, msk);
  __syncthreads();
  if ((t & 63) == 0) sred[t >> 6] = sq;
  __syncthreads();
  float var = (sred[0] + sred[1] + sred[2] + sred[3]) * (1.f / D);
  float rs = rsqrtf(var + 1e-5f);

  float4 g = *(const float4*)(gamma + t * 4);
  float4 be = *(const float4*)(beta + t * 4);
  float4 y;
  y.x = dx * rs * g.x + be.x;
  y.y = dy * rs * g.y + be.y;
  y.z = dz * rs * g.z + be.z;
  y.w = dw * rs * g.w + be.w;
  if (OUT_F32) {
    *(float4*)(outf + bidx) = y;
  } else {
    uint2 o;
    o.x = (unsigned)f2bf(y.x) | ((unsigned)f2bf(y.y) << 16);
    o.y = (unsigned)f2bf(y.z) | ((unsigned)f2bf(y.w) << 16);
    *(uint2*)(outb + bidx) = o;
  }
}

extern "C" void kernel_launch(void* const* d_in, const int* in_sizes, int n_in,
                              void* d_out, int out_size, void* d_ws, size_t ws_size,
                              hipStream_t stream) {
  const float* x   = (const float*)d_in[0];
  const float* wq  = (const float*)d_in[1];
  const float* bq  = (const float*)d_in[2];
  const float* wk  = (const float*)d_in[3];
  const float* bk  = (const float*)d_in[4];
  const float* wv  = (const float*)d_in[5];
  const float* bv  = (const float*)d_in[6];
  const float* wo  = (const float*)d_in[7];
  const float* bo  = (const float*)d_in[8];
  const float* w1  = (const float*)d_in[9];
  const float* b1  = (const float*)d_in[10];
  const float* w2  = (const float*)d_in[11];
  const float* b2  = (const float*)d_in[12];
  const float* g1  = (const float*)d_in[13];
  const float* be1 = (const float*)d_in[14];
  const float* g2  = (const float*)d_in[15];
  const float* be2 = (const float*)d_in[16];

  char* ws = (char*)d_ws;
  size_t off = 0;
  auto alloc = [&](size_t bytes) {
    char* p = ws + off;
    off += (bytes + 255) & ~(size_t)255;
    return p;
  };

  unsigned short* wqkvT = (unsigned short*)alloc((size_t)3 * D * D * 2);  // [3072][1024]
  unsigned short* woT = (unsigned short*)alloc((size_t)D * D * 2);
  unsigned short* w1T = (unsigned short*)alloc((size_t)D * DFF * 2);
  unsigned short* w2T = (unsigned short*)alloc((size_t)DFF * D * 2);
  unsigned short* xb  = (unsigned short*)alloc((size_t)NT * D * 2);   // reused as x1b
  unsigned short* big = (unsigned short*)alloc((size_t)NT * DFF * 2); // q|k|ctx|vt, later ff
  unsigned short* qb  = big;
  unsigned short* kb_ = big + (size_t)NT * D;
  unsigned short* ctb = big + (size_t)2 * NT * D;
  unsigned short* vtb = big + (size_t)3 * NT * D;                     // per-head V^T (16 MiB)
  unsigned short* O1  = (unsigned short*)alloc((size_t)NT * D * 2);   // attn_out (WO out)
  unsigned short* O2  = (unsigned short*)alloc((size_t)NT * D * 2);   // ff2
  unsigned short* x1b = xb;
  unsigned short* ffb = big;
  unsigned short* attn_out = O1;  // WO output (bf16, residual fused)
  unsigned short* ff2 = O2;       // FF2 output (bf16, residual fused)
  (void)ws_size; (void)in_sizes; (void)n_in; (void)out_size;

  // 1. convert x + all weights (transposed) to bf16 in 2 launches
  cvt_bf16_kernel<<<NT * D / 2048, 256, 0, stream>>>(x, xb, NT * D);
  transpose_cvt_all_kernel<<<3072, 256, 0, stream>>>(wq, wk, wv, wo, w1, w2,
                                                     wqkvT, woT, w1T, w2T);

  // 2. fused QKV projection, BNW=2: grid 768 = 3 balanced rounds at 1 block/CU
  //    (BNW=4's 384 blocks = 1.5 rounds with a half-idle tail)
  gemm256_kernel<2, 3, false><<<(3 * D / 128) * (NT / 256), 512, 0, stream>>>(
      xb, wqkvT, bq, bk, bv, nullptr, qb, kb_, vtb, NT, 3 * D, D);

  // 3. attention (full key range, 256 q-rows/block — R14 measured config)
  attn_kernel<<<dim3(S / 256, B * H), 512, 0, stream>>>(qb, kb_, vtb, ctb);

  // 4. output projection with fused residual: attn_out = ctx @ wo + bo + x  (bf16)
  gemm256_kernel<2, 4, false><<<(D / 128) * (NT / 256), 512, 0, stream>>>(
      ctb, woT, bo, nullptr, nullptr, xb, attn_out, nullptr, nullptr, NT, D, D);

  // 5. x1 = LN(attn_out) -> bf16
  ln_kernel<false><<<NT, 256, 0, stream>>>(attn_out, g1, be1, nullptr, x1b);

  // 6. FF (FF2 with fused bf16 residual: ff2 = relu(x1 @ w1 + b1) @ w2 + b2 + x1)
  gemm256_kernel<4, 1, true><<<(DFF / 256) * (NT / 256), 512, 0, stream>>>(
      x1b, w1T, b1, nullptr, nullptr, nullptr, ffb, nullptr, nullptr, NT, DFF, D);
  gemm256_kernel<2, 4, false><<<(D / 128) * (NT / 256), 512, 0, stream>>>(
      ffb, w2T, b2, nullptr, nullptr, x1b, ff2, nullptr, nullptr, NT, D, DFF);

  // 7. out = LN(ff2) -> fp32
  ln_kernel<true><<<NT, 256, 0, stream>>>(ff2, g2, be2, (float*)d_out, nullptr);
}

// Round 17
// 403.060 us; speedup vs baseline: 1.0344x; 1.0243x over previous
//
#include <hip/hip_runtime.h>
#include <hip/hip_bf16.h>

#define DEV __device__ __forceinline__

typedef __attribute__((ext_vector_type(8))) short bf16x8;
typedef __attribute__((ext_vector_type(4))) float f32x4;

constexpr int B = 4, S = 2048, D = 1024, H = 16, DK = 64, DFF = 4096;
constexpr int NT = B * S;  // 8192 tokens
constexpr float QSCALE = 0.125f * 1.44269504088896f;  // 1/sqrt(dk) * log2(e)

#if __has_builtin(__builtin_amdgcn_exp2f)
#define EXP2(x) __builtin_amdgcn_exp2f(x)
#else
#define EXP2(x) exp2f(x)
#endif

#define BARRIER()                         \
  asm volatile("" ::: "memory");          \
  __builtin_amdgcn_s_barrier();           \
  asm volatile("" ::: "memory")

DEV unsigned short f2bf(float f) {
  return __builtin_bit_cast(unsigned short, __float2bfloat16(f));
}
DEV float bf2f(unsigned short u) { return __uint_as_float((unsigned)u << 16); }

// async global->LDS 16B: lds base must be wave-uniform; each lane deposits at base+lane*16
DEV void gld16(unsigned short* ldsbase, const unsigned short* g, int lane) {
#if __has_builtin(__builtin_amdgcn_global_load_lds)
  __builtin_amdgcn_global_load_lds((const __attribute__((address_space(1))) unsigned int*)g,
                                   (__attribute__((address_space(3))) unsigned int*)ldsbase,
                                   16, 0, 0);
#else
  *(uint4*)(ldsbase + lane * 8) = *(const uint4*)g;
#endif
}

// ---------------- fp32 -> bf16 elementwise ----------------
__global__ __launch_bounds__(256) void cvt_bf16_kernel(const float* __restrict__ in,
                                                       unsigned short* __restrict__ out, int n) {
  int i = (blockIdx.x * 256 + threadIdx.x) * 8;
  if (i >= n) return;
  float4 a = *(const float4*)(in + i);
  float4 b = *(const float4*)(in + i + 4);
  uint4 o;
  o.x = f2bf(a.x) | ((unsigned)f2bf(a.y) << 16);
  o.y = f2bf(a.z) | ((unsigned)f2bf(a.w) << 16);
  o.z = f2bf(b.x) | ((unsigned)f2bf(b.y) << 16);
  o.w = f2bf(b.z) | ((unsigned)f2bf(b.w) << 16);
  *(uint4*)(out + i) = o;
}

// ---------------- all 6 weights: fp32 (R x C) -> bf16 transposed (C x R), one launch ------
__global__ __launch_bounds__(256) void transpose_cvt_all_kernel(
    const float* __restrict__ wq, const float* __restrict__ wk, const float* __restrict__ wv,
    const float* __restrict__ wo, const float* __restrict__ w1, const float* __restrict__ w2,
    unsigned short* __restrict__ wqkvT, unsigned short* __restrict__ woT,
    unsigned short* __restrict__ w1T, unsigned short* __restrict__ w2T) {
  __shared__ unsigned short tile[64][72];
  int bid = blockIdx.x;
  const float* in;
  unsigned short* out;
  int R, C, tb;
  if (bid < 1024) {  // wq|wk|wv|wo: 1024x1024, 256 tiles each
    int wsel = bid >> 8;
    tb = bid & 255;
    R = 1024; C = 1024;
    in = wsel == 0 ? wq : wsel == 1 ? wk : wsel == 2 ? wv : wo;
    out = wsel < 3 ? wqkvT + (size_t)wsel * D * D : woT;
  } else if (bid < 2048) {  // w1: 1024x4096
    tb = bid - 1024; R = 1024; C = 4096; in = w1; out = w1T;
  } else {                  // w2: 4096x1024
    tb = bid - 2048; R = 4096; C = 1024; in = w2; out = w2T;
  }
  int gx = C >> 6;
  int rb = (tb / gx) * 64, cb = (tb % gx) * 64;
  int t = threadIdx.x;
#pragma unroll
  for (int i = 0; i < 16; ++i) {
    int c = t + i * 256;
    int r = c >> 6, cc = c & 63;
    tile[cc][r] = f2bf(in[(size_t)(rb + r) * C + cb + cc]);
  }
  __syncthreads();
#pragma unroll
  for (int i = 0; i < 16; ++i) {
    int c = t + i * 256;
    int rr = c >> 6, cc = c & 63;
    out[(size_t)(cb + rr) * R + rb + cc] = tile[rr][cc];
  }
}

// ---------------- 256-tile GEMM, 8-phase K-half-plane schedule (R13, 419us) ----------------
// OMODE: 0 = fp32 out0, 1 = bf16 out0 (RELU opt), 3 = QKV routing, 4 = bf16 acc+bias+res
template <int BNW, int OMODE, bool RELU>
__global__ __launch_bounds__(512) void gemm256_kernel(const unsigned short* __restrict__ A,
                                                      const unsigned short* __restrict__ WT,
                                                      const float* __restrict__ bias0,
                                                      const float* __restrict__ bias1,
                                                      const float* __restrict__ bias2,
                                                      const unsigned short* __restrict__ res,
                                                      void* __restrict__ out0,
                                                      void* __restrict__ out1,
                                                      void* __restrict__ out2,
                                                      int M, int N, int K) {
  constexpr int BN = BNW * 64;
  __shared__ __align__(16) unsigned short sA[2][2][256 * 32];
  __shared__ __align__(16) unsigned short sB[2][2][BN * 32];

  int t = threadIdx.x, w = t >> 6, l = t & 63;
  int ll = l & 15, lh = l >> 4;

  // T1: XCD-aware swizzle (all grids here are divisible by 8)
  int lin = blockIdx.x, nwg = gridDim.x;
  int wg = (nwg & 7) == 0 ? (lin & 7) * (nwg >> 3) + (lin >> 3) : lin;
  int gx = N / BN;
  int bn = wg % gx, bm = wg / gx;

  const int wm = (w >> 2) * 128, wn = (w & 3) * (BNW * 16);
  const int ua = (lh ^ ((ll >> 1) & 3)) * 8;  // ds_read unit offset (shorts), per-thread const

  f32x4 acc[8][BNW] = {};

  const int pr = t >> 2, up = t & 3;
  const int ulog = up ^ ((pr >> 1) & 3);
  const unsigned short* gA0 = A + ((size_t)bm * 256 + pr) * K + ulog * 8;
  const unsigned short* gB0 = WT + ((size_t)bn * BN + pr) * K + ulog * 8;

  auto stgA = [&](int buf, int kh, int tile) {
    const unsigned short* s = gA0 + (size_t)tile * 64 + kh * 32;
    gld16(&sA[buf][kh][w * 512], s, l);
    gld16(&sA[buf][kh][4096 + w * 512], s + (size_t)128 * K, l);
  };
  auto stgB = [&](int buf, int kh, int tile) {
    const unsigned short* s = gB0 + (size_t)tile * 64 + kh * 32;
    gld16(&sB[buf][kh][w * 512], s, l);
    if constexpr (BNW == 4) gld16(&sB[buf][kh][4096 + w * 512], s + (size_t)128 * K, l);
  };

  const int NK = K >> 6;
  stgA(0, 0, 0); stgB(0, 0, 0);
  stgA(0, 1, 0); stgB(0, 1, 0);
  stgA(1, 0, 1); stgB(1, 0, 1);
  if constexpr (BNW == 4) asm volatile("s_waitcnt vmcnt(4)" ::: "memory");
  else                    asm volatile("s_waitcnt vmcnt(3)" ::: "memory");
  BARRIER();

  bf16x8 bfr[BNW];
  for (int it = 0; it < NK; it += 2) {
    const bool more = it + 2 < NK;
#pragma unroll
    for (int ph = 0; ph < 8; ++ph) {
      const int tb = ph >> 2;
      const int kh = (ph >> 1) & 1;
      const int mq = ph & 1;
      bf16x8 af[4];
      if (mq == 0) {
#pragma unroll
        for (int nt = 0; nt < BNW; ++nt)
          bfr[nt] = *(const bf16x8*)(&sB[tb][kh][(wn + nt * 16 + ll) * 32 + ua]);
      }
#pragma unroll
      for (int i = 0; i < 4; ++i)
        af[i] = *(const bf16x8*)(&sA[tb][kh][(wm + (mq * 4 + i) * 16 + ll) * 32 + ua]);
      if (ph == 0) stgA(1, 1, it + 1);
      else if (ph == 1) stgB(1, 1, it + 1);
      else if (more) {
        if (ph == 2) stgA(0, 0, it + 2);
        else if (ph == 3) stgB(0, 0, it + 2);
        else if (ph == 4) stgA(0, 1, it + 2);
        else if (ph == 5) stgB(0, 1, it + 2);
        else if (ph == 6) stgA(1, 0, it + 3);
        else stgB(1, 0, it + 3);
      }
      BARRIER();
      __builtin_amdgcn_s_setprio(1);
#pragma unroll
      for (int i = 0; i < 4; ++i)
#pragma unroll
        for (int nt = 0; nt < BNW; ++nt)
          acc[mq * 4 + i][nt] =
              __builtin_amdgcn_mfma_f32_16x16x32_bf16(af[i], bfr[nt], acc[mq * 4 + i][nt], 0, 0, 0);
      __builtin_amdgcn_s_setprio(0);
      if (ph == 3 || ph == 7) {
        if (more) {
          if constexpr (BNW == 4) asm volatile("s_waitcnt vmcnt(4)" ::: "memory");
          else                    asm volatile("s_waitcnt vmcnt(3)" ::: "memory");
        } else {
          asm volatile("s_waitcnt vmcnt(0)" ::: "memory");
        }
      }
      BARRIER();
    }
  }

  // epilogue
#pragma unroll
  for (int mt = 0; mt < 8; ++mt) {
#pragma unroll
    for (int nt = 0; nt < BNW; ++nt) {
      int col = bn * BN + wn + nt * 16 + ll;
      int row0 = bm * 256 + wm + mt * 16 + lh * 4;
      if constexpr (OMODE == 3) {
        int sec = col >> 10, c = col & 1023;
        float bv = (sec == 0 ? bias0 : (sec == 1 ? bias1 : bias2))[c];
        if (sec == 2) {  // per-head transposed V
          int b_ = row0 >> 11, s_ = row0 & 2047;
          size_t vr = ((size_t)(b_ * H + (c >> 6)) * 64 + (c & 63)) * S + s_;
          uint2 pk;
          pk.x = (unsigned)f2bf(acc[mt][nt][0] + bv) | ((unsigned)f2bf(acc[mt][nt][1] + bv) << 16);
          pk.y = (unsigned)f2bf(acc[mt][nt][2] + bv) | ((unsigned)f2bf(acc[mt][nt][3] + bv) << 16);
          *(uint2*)((unsigned short*)out2 + vr) = pk;
        } else {
          unsigned short* o = sec == 0 ? (unsigned short*)out0 : (unsigned short*)out1;
          float sc_ = sec == 0 ? QSCALE : 1.f;
#pragma unroll
          for (int r = 0; r < 4; ++r)
            o[(size_t)(row0 + r) * 1024 + c] = f2bf((acc[mt][nt][r] + bv) * sc_);
        }
      } else {
        float bv = bias0[col];
#pragma unroll
        for (int r = 0; r < 4; ++r) {
          float v = acc[mt][nt][r] + bv;
          if (RELU) v = fmaxf(v, 0.f);
          if (OMODE == 4) {
            v += bf2f(res[(size_t)(row0 + r) * N + col]);
            ((unsigned short*)out0)[(size_t)(row0 + r) * N + col] = f2bf(v);
          } else if (OMODE == 1)
            ((unsigned short*)out0)[(size_t)(row0 + r) * N + col] = f2bf(v);
          else
            ((float*)out0)[(size_t)(row0 + r) * N + col] = v;
        }
      }
    }
  }
}

// ---------------- Flash attention, LDS-staged K/V, full key range (R14, 114us) ----------------
// 8 waves x 32 q-rows = 256 q-rows/block. Defer-max softmax, 64-VGPR measured config.
__global__ __launch_bounds__(512) void attn_kernel(const unsigned short* __restrict__ q,
                                                   const unsigned short* __restrict__ k,
                                                   const unsigned short* __restrict__ vt,
                                                   unsigned short* __restrict__ ctx) {
  __shared__ __align__(16) unsigned short sK[2][64 * 64];
  __shared__ __align__(16) unsigned short sV[2][64 * 64];
  __shared__ __align__(16) unsigned short sP[8][16 * 72];
  int t = threadIdx.x, w = t >> 6, l = t & 63;
  int ll = l & 15, lh = l >> 4;
  int bh = blockIdx.y;
  int q0 = blockIdx.x * 256 + w * 32;
  const size_t base = (size_t)(bh >> 4) * S * D + (size_t)(bh & 15) * DK;
  const size_t vtbase = (size_t)bh * 64 * S;
  unsigned short* sPw = sP[w];

  const int srow = t >> 3;
  const int scol = 8 * ((t & 7) ^ (srow & 7));
  const unsigned short* gk = k + base + (size_t)srow * D + scol;
  const unsigned short* gv = vt + vtbase + (size_t)srow * S + scol;

  bf16x8 qf[2][2];
#pragma unroll
  for (int qs = 0; qs < 2; ++qs)
#pragma unroll
    for (int kk = 0; kk < 2; ++kk)
      qf[qs][kk] = *(const bf16x8*)(q + base + (size_t)(q0 + qs * 16 + ll) * D + kk * 32 + lh * 8);

  f32x4 cacc[2][4] = {};
  float m[2] = {-1e30f, -1e30f}, lsum[2] = {0.f, 0.f};

  const int swz = (ll & 7) << 3;

  gld16(&sK[0][w * 512], gk, l);
  gld16(&sV[0][w * 512], gv, l);
  asm volatile("s_waitcnt vmcnt(0)" ::: "memory");
  __syncthreads();

  int cur = 0;
  for (int step = 0; step < 32; ++step) {
    int kb = step * 64;
    if (step < 31) {
      gld16(&sK[cur ^ 1][w * 512], gk + (size_t)(kb + 64) * D, l);
      gld16(&sV[cur ^ 1][w * 512], gv + (kb + 64), l);
    }
    const unsigned short* sKc = sK[cur];
    const unsigned short* sVc = sV[cur];

    bf16x8 kf[4][2];
#pragma unroll
    for (int nt = 0; nt < 4; ++nt)
#pragma unroll
      for (int kk = 0; kk < 2; ++kk)
        kf[nt][kk] = *(const bf16x8*)(sKc + (nt * 16 + ll) * 64 + ((kk * 32 + lh * 8) ^ swz));

    bf16x8 pf[2][2];
#pragma unroll
    for (int qs = 0; qs < 2; ++qs) {
      f32x4 sc[4] = {};
      __builtin_amdgcn_s_setprio(1);
#pragma unroll
      for (int nt = 0; nt < 4; ++nt) {
        sc[nt] = __builtin_amdgcn_mfma_f32_16x16x32_bf16(kf[nt][0], qf[qs][0], sc[nt], 0, 0, 0);
        sc[nt] = __builtin_amdgcn_mfma_f32_16x16x32_bf16(kf[nt][1], qf[qs][1], sc[nt], 0, 0, 0);
      }
      __builtin_amdgcn_s_setprio(0);
      float tm = -1e30f;
#pragma unroll
      for (int nt = 0; nt < 4; ++nt)
#pragma unroll
        for (int r = 0; r < 4; ++r) tm = fmaxf(tm, sc[nt][r]);
      tm = fmaxf(tm, __shfl_xor(tm, 16));
      tm = fmaxf(tm, __shfl_xor(tm, 32));
      if (!__all(tm <= m[qs] + 8.0f)) {  // defer-max
        float mn = fmaxf(m[qs], tm);
        float rsc = EXP2(m[qs] - mn);
        lsum[qs] *= rsc;
#pragma unroll
        for (int dt = 0; dt < 4; ++dt)
#pragma unroll
          for (int r = 0; r < 4; ++r) cacc[qs][dt][r] *= rsc;
        m[qs] = mn;
      }
      float p[4][4], ps = 0.f;
#pragma unroll
      for (int nt = 0; nt < 4; ++nt)
#pragma unroll
        for (int r = 0; r < 4; ++r) {
          p[nt][r] = EXP2(sc[nt][r] - m[qs]);
          ps += p[nt][r];
        }
      ps += __shfl_xor(ps, 16);
      ps += __shfl_xor(ps, 32);
      lsum[qs] += ps;
#pragma unroll
      for (int nt = 0; nt < 4; ++nt) {
        uint2 pk;
        pk.x = (unsigned)f2bf(p[nt][0]) | ((unsigned)f2bf(p[nt][1]) << 16);
        pk.y = (unsigned)f2bf(p[nt][2]) | ((unsigned)f2bf(p[nt][3]) << 16);
        *(uint2*)(&sPw[ll * 72 + nt * 16 + lh * 4]) = pk;
      }
      pf[qs][0] = *(const bf16x8*)(&sPw[ll * 72 + lh * 8]);
      pf[qs][1] = *(const bf16x8*)(&sPw[ll * 72 + 32 + lh * 8]);
    }

    bf16x8 vf[4][2];
#pragma unroll
    for (int dt = 0; dt < 4; ++dt)
#pragma unroll
      for (int kt = 0; kt < 2; ++kt)
        vf[dt][kt] = *(const bf16x8*)(sVc + (dt * 16 + ll) * 64 + ((kt * 32 + lh * 8) ^ swz));
    __builtin_amdgcn_s_setprio(1);
#pragma unroll
    for (int qs = 0; qs < 2; ++qs)
#pragma unroll
      for (int dt = 0; dt < 4; ++dt)
#pragma unroll
        for (int kt = 0; kt < 2; ++kt)
          cacc[qs][dt] = __builtin_amdgcn_mfma_f32_16x16x32_bf16(pf[qs][kt], vf[dt][kt], cacc[qs][dt], 0, 0, 0);
    __builtin_amdgcn_s_setprio(0);

    asm volatile("s_waitcnt vmcnt(0)" ::: "memory");
    __syncthreads();
    cur ^= 1;
  }

  // epilogue: normalized bf16 ctx directly
#pragma unroll
  for (int qs = 0; qs < 2; ++qs) {
    float inv[4];
#pragma unroll
    for (int r = 0; r < 4; ++r) inv[r] = 1.0f / __shfl(lsum[qs], lh * 4 + r);
#pragma unroll
    for (int dt = 0; dt < 4; ++dt) {
#pragma unroll
      for (int r = 0; r < 4; ++r) {
        int row = q0 + qs * 16 + lh * 4 + r;
        ctx[base + (size_t)row * D + dt * 16 + ll] = f2bf(cacc[qs][dt][r] * inv[r]);
      }
    }
  }
}

// ---------------- LayerNorm of a single bf16 buffer (residual pre-added) ----------------
template <bool OUT_F32>
__global__ __launch_bounds__(256) void ln_kernel(const unsigned short* __restrict__ a,
                                                 const float* __restrict__ gamma,
                                                 const float* __restrict__ beta,
                                                 float* __restrict__ outf,
                                                 unsigned short* __restrict__ outb) {
  __shared__ float sred[8];
  size_t row = blockIdx.x;
  int t = threadIdx.x;
  size_t bidx = row * D + t * 4;
  ushort4 u = *(const ushort4*)(a + bidx);
  float4 x;
  x.x = bf2f(u.x); x.y = bf2f(u.y); x.z = bf2f(u.z); x.w = bf2f(u.w);

  float s = x.x + x.y + x.z + x.w;
#pragma unroll
  for (int msk = 32; msk; msk >>= 1) s += __shfl_xor(s, msk);
  if ((t & 63) == 0) sred[t >> 6] = s;
  __syncthreads();
  float mu = (sred[0] + sred[1] + sred[2] + sred[3]) * (1.f / D);

  float dx = x.x - mu, dy = x.y - mu, dz = x.z - mu, dw = x.w - mu;
  float sq = dx * dx + dy * dy + dz * dz + dw * dw;
#pragma unroll
  for (int msk = 32; msk; msk >>= 1) sq += __shfl_xor(sq, msk);
  __syncthreads();
  if ((t & 63) == 0) sred[t >> 6] = sq;
  __syncthreads();
  float var = (sred[0] + sred[1] + sred[2] + sred[3]) * (1.f / D);
  float rs = rsqrtf(var + 1e-5f);

  float4 g = *(const float4*)(gamma + t * 4);
  float4 be = *(const float4*)(beta + t * 4);
  float4 y;
  y.x = dx * rs * g.x + be.x;
  y.y = dy * rs * g.y + be.y;
  y.z = dz * rs * g.z + be.z;
  y.w = dw * rs * g.w + be.w;
  if (OUT_F32) {
    *(float4*)(outf + bidx) = y;
  } else {
    uint2 o;
    o.x = (unsigned)f2bf(y.x) | ((unsigned)f2bf(y.y) << 16);
    o.y = (unsigned)f2bf(y.z) | ((unsigned)f2bf(y.w) << 16);
    *(uint2*)(outb + bidx) = o;
  }
}

extern "C" void kernel_launch(void* const* d_in, const int* in_sizes, int n_in,
                              void* d_out, int out_size, void* d_ws, size_t ws_size,
                              hipStream_t stream) {
  const float* x   = (const float*)d_in[0];
  const float* wq  = (const float*)d_in[1];
  const float* bq  = (const float*)d_in[2];
  const float* wk  = (const float*)d_in[3];
  const float* bk  = (const float*)d_in[4];
  const float* wv  = (const float*)d_in[5];
  const float* bv  = (const float*)d_in[6];
  const float* wo  = (const float*)d_in[7];
  const float* bo  = (const float*)d_in[8];
  const float* w1  = (const float*)d_in[9];
  const float* b1  = (const float*)d_in[10];
  const float* w2  = (const float*)d_in[11];
  const float* b2  = (const float*)d_in[12];
  const float* g1  = (const float*)d_in[13];
  const float* be1 = (const float*)d_in[14];
  const float* g2  = (const float*)d_in[15];
  const float* be2 = (const float*)d_in[16];

  char* ws = (char*)d_ws;
  size_t off = 0;
  auto alloc = [&](size_t bytes) {
    char* p = ws + off;
    off += (bytes + 255) & ~(size_t)255;
    return p;
  };

  unsigned short* wqkvT = (unsigned short*)alloc((size_t)3 * D * D * 2);  // [3072][1024]
  unsigned short* woT = (unsigned short*)alloc((size_t)D * D * 2);
  unsigned short* w1T = (unsigned short*)alloc((size_t)D * DFF * 2);
  unsigned short* w2T = (unsigned short*)alloc((size_t)DFF * D * 2);
  unsigned short* xb  = (unsigned short*)alloc((size_t)NT * D * 2);   // reused as x1b
  unsigned short* big = (unsigned short*)alloc((size_t)NT * DFF * 2); // q|k|ctx|vt, later ff
  unsigned short* qb  = big;
  unsigned short* kb_ = big + (size_t)NT * D;
  unsigned short* ctb = big + (size_t)2 * NT * D;
  unsigned short* vtb = big + (size_t)3 * NT * D;                     // per-head V^T (16 MiB)
  unsigned short* O1  = (unsigned short*)alloc((size_t)NT * D * 2);   // attn_out (WO out)
  unsigned short* O2  = (unsigned short*)alloc((size_t)NT * D * 2);   // ff2
  unsigned short* x1b = xb;
  unsigned short* ffb = big;
  unsigned short* attn_out = O1;  // WO output (bf16, residual fused)
  unsigned short* ff2 = O2;       // FF2 output (bf16, residual fused)
  (void)ws_size; (void)in_sizes; (void)n_in; (void)out_size;

  // 1. convert x + all weights (transposed) to bf16 in 2 launches
  cvt_bf16_kernel<<<NT * D / 2048, 256, 0, stream>>>(x, xb, NT * D);
  transpose_cvt_all_kernel<<<3072, 256, 0, stream>>>(wq, wk, wv, wo, w1, w2,
                                                     wqkvT, woT, w1T, w2T);

  // 2. fused QKV projection, BNW=4 (R14 measured config; BNW=2 regressed ~7us in R16 —
  //    halving BN halves per-block B-reuse, outweighing the balanced 3-round grid)
  gemm256_kernel<4, 3, false><<<(3 * D / 256) * (NT / 256), 512, 0, stream>>>(
      xb, wqkvT, bq, bk, bv, nullptr, qb, kb_, vtb, NT, 3 * D, D);

  // 3. attention (full key range, 256 q-rows/block — R14 measured config)
  attn_kernel<<<dim3(S / 256, B * H), 512, 0, stream>>>(qb, kb_, vtb, ctb);

  // 4. output projection with fused residual: attn_out = ctx @ wo + bo + x  (bf16)
  gemm256_kernel<2, 4, false><<<(D / 128) * (NT / 256), 512, 0, stream>>>(
      ctb, woT, bo, nullptr, nullptr, xb, attn_out, nullptr, nullptr, NT, D, D);

  // 5. x1 = LN(attn_out) -> bf16
  ln_kernel<false><<<NT, 256, 0, stream>>>(attn_out, g1, be1, nullptr, x1b);

  // 6. FF (FF2 with fused bf16 residual: ff2 = relu(x1 @ w1 + b1) @ w2 + b2 + x1)
  gemm256_kernel<4, 1, true><<<(DFF / 256) * (NT / 256), 512, 0, stream>>>(
      x1b, w1T, b1, nullptr, nullptr, nullptr, ffb, nullptr, nullptr, NT, DFF, D);
  gemm256_kernel<2, 4, false><<<(D / 128) * (NT / 256), 512, 0, stream>>>(
      ffb, w2T, b2, nullptr, nullptr, x1b, ff2, nullptr, nullptr, NT, D, DFF);

  // 7. out = LN(ff2) -> fp32
  ln_kernel<true><<<NT, 256, 0, stream>>>(ff2, g2, be2, (float*)d_out, nullptr);
}